// Round 5
// baseline (543.917 us; speedup 1.0000x reference)
//
#include <hip/hip_runtime.h>

// ---------------------------------------------------------------------------
// SynthesisLayer (StyleGAN2 modulated conv) on MI355X.
//   s[b,i]   = w[b,:] @ sw[i,:]^T * SS + sb[i]
//   csq[o,i] = CS^2 * sum_t cw[o,i,t]^2
//   sig[b,o] = rsqrt( sum_i s^2[b,i]*csq[o,i] + eps )
//   x'[b,h,w,i] = bf16( x[b,i,h,w] * s[b,i] )
//   cwt slab[(oblk,ic)]: 36 taps*4g x 64 o x 8 j bf16 (contiguous 36,864 B)
//   y = sig * conv(x', cwt) + nw*noise + bias; leaky 0.2
//
// k_conv v6: software-pipelined tap stream (R4 lesson: occupancy saturated;
// per-wave serialization load->wait->TAP was the binder - register reuse
// created WAR hazards preventing load hoisting).
//   - A/B fragments double-buffered in DISTINCT registers (A0/A1,B0/B1);
//     stage s+1 loads issued before stage s's TAP -> waits become counted,
//     operands in flight one full TAP burst (~310 cyc) ahead.
//   - A(tap0) of ic+1 prefetched before the barrier (global, xs-independent).
//   - staging addresses hoisted to a 6-slot unrolled pointer table.
//   - setprio dropped (risks pinning; null for non-phase-split GEMM, m190).
// Geometry unchanged from v5: wave = 64o x 64px x 1 row, acc 64 f32;
// xs dbuf 2x24,576 B -> 3 blocks/CU; conflict-free slot swizzle f(c)=(c>>1)&3;
// A from global cwt slabs; XCD dispatch chunking.
// ---------------------------------------------------------------------------

typedef __attribute__((ext_vector_type(8))) short short8;    // 8 x bf16
typedef __attribute__((ext_vector_type(4))) float f32x4;     // mfma acc

#define STYLE_SCALE 0.044194173824159216f   /* 1/sqrt(512)  */
#define CONV_SCALE  0.014731391274719742f   /* 1/sqrt(4608) */
#define CS2         (1.0f/4608.0f)

static __device__ __forceinline__ unsigned short f2bf(float x) {
    union { float f; unsigned int u; } a; a.f = x;
    unsigned int r = a.u + 0x7fffu + ((a.u >> 16) & 1u);    // round-nearest-even
    return (unsigned short)(r >> 16);
}

static __device__ __forceinline__ void gl_lds16(const void* g, void* l) {
    __builtin_amdgcn_global_load_lds(
        (const __attribute__((address_space(1))) unsigned int*)g,
        (__attribute__((address_space(3))) unsigned int*)l, 16, 0, 0);
}

// ---------------- kernel 1: style linear  s[16,512], split-K x4 -----------
__global__ void k_style(const float* __restrict__ w, const float* __restrict__ sw,
                        const float* __restrict__ sb, float* __restrict__ s) {
    int b = blockIdx.y, j0 = blockIdx.x * 64, t = threadIdx.x;
    __shared__ float wl[512];
    __shared__ float part[256];
    wl[t] = w[b*512 + t]; wl[t+256] = w[b*512 + t + 256];
    __syncthreads();
    int jl = t & 63, seg = t >> 6;
    const float4* row = (const float4*)(sw + (size_t)(j0 + jl)*512) + seg*32;
    const float*  wv  = wl + seg*128;
    float acc = 0.f;
#pragma unroll 4
    for (int k = 0; k < 32; ++k) {
        float4 v = row[k];
        acc += v.x*wv[4*k] + v.y*wv[4*k+1] + v.z*wv[4*k+2] + v.w*wv[4*k+3];
    }
    part[t] = acc;
    __syncthreads();
    if (t < 64)
        s[b*512 + j0 + t] = (part[t] + part[t+64] + part[t+128] + part[t+192])
                            * STYLE_SCALE + sb[j0 + t];
}

// ------- kernel 2: fused csq + weight pack (one cw row per block) ---------
// cwt layout: slab(oblk,ic) contiguous: [(oblk*16+ic)][tap*4+g][o&63][8j]
__global__ void k_wprep(const float* __restrict__ cw, float* __restrict__ csq,
                        unsigned short* __restrict__ cwt) {
    int o = blockIdx.x, t = threadIdx.x;
    __shared__ float row[4608];
    const float4* src = (const float4*)(cw + (size_t)o*4608);
    for (int i = t; i < 1152; i += 256) ((float4*)row)[i] = src[i];
    __syncthreads();
    // csq
#pragma unroll
    for (int it = 0; it < 2; ++it) {
        int i = t + it*256;
        float a = 0.f;
#pragma unroll
        for (int k = 0; k < 9; ++k) { float v = row[i*9 + k]; a += v*v; }
        csq[(size_t)o*512 + i] = a * CS2;
    }
    // cwt pack
    for (int p = t; p < 576; p += 256) {
        int ic = p / 36, rem = p % 36;
        int tap = rem >> 2, g = rem & 3;
        int i0 = ic*32 + g*8;
        union { unsigned short us[8]; uint4 q; } u;
#pragma unroll
        for (int j = 0; j < 8; ++j)
            u.us[j] = f2bf(row[(i0 + j)*9 + tap] * CONV_SCALE);
        size_t dst = (((size_t)(o >> 6)*16 + ic)*36 + rem)*64 + (o & 63);
        *(uint4*)(cwt + dst*8) = u.q;
    }
}

// ---------------- kernel 3: sigma[b,o], split-K x4 ------------------------
__global__ void k_sigma(const float* __restrict__ s, const float* __restrict__ csq,
                        float* __restrict__ sig) {
    int b = blockIdx.y, o0 = blockIdx.x * 64, t = threadIdx.x;
    __shared__ float s2l[512];
    __shared__ float part[256];
    float v0 = s[b*512 + t], v1 = s[b*512 + t + 256];
    s2l[t] = v0*v0; s2l[t+256] = v1*v1;
    __syncthreads();
    int ol = t & 63, seg = t >> 6;
    const float4* row = (const float4*)(csq + (size_t)(o0 + ol)*512) + seg*32;
    const float*  sv  = s2l + seg*128;
    float acc = 0.f;
#pragma unroll 4
    for (int k = 0; k < 32; ++k) {
        float4 c = row[k];
        acc += c.x*sv[4*k] + c.y*sv[4*k+1] + c.z*sv[4*k+2] + c.w*sv[4*k+3];
    }
    part[t] = acc;
    __syncthreads();
    if (t < 64)
        sig[b*512 + o0 + t] = 1.0f / sqrtf(part[t] + part[t+64] + part[t+128]
                                           + part[t+192] + 1e-6f);
}

// ------- kernel 4: x' transpose+modulate -> xt[b][h*64+w][c] bf16 ---------
__global__ void k_xt(const float* __restrict__ x, const float* __restrict__ s,
                     unsigned short* __restrict__ xt) {
    int h = blockIdx.x, b = blockIdx.y, t = threadIdx.x;
    __shared__ float tile[64][65];
    __shared__ float sl[64];
    for (int c0 = 0; c0 < 512; c0 += 64) {
        if (t < 64) sl[t] = s[b*512 + c0 + t];
#pragma unroll
        for (int it = 0; it < 4; ++it) {
            int idx = t + it*256;            // [c(64)][w4(16)]
            int c = idx >> 4, w4 = (idx & 15) * 4;
            float4 v = *(const float4*)(x + ((size_t)(b*512 + c0 + c)*4096) + h*64 + w4);
            tile[c][w4]   = v.x; tile[c][w4+1] = v.y;
            tile[c][w4+2] = v.z; tile[c][w4+3] = v.w;
        }
        __syncthreads();
#pragma unroll
        for (int it = 0; it < 2; ++it) {
            int idx = t + it*256;            // [wq(64)][g(8)]
            int wq = idx >> 3, c = (idx & 7) * 8;
            union { unsigned short us[8]; uint4 q; } u;
#pragma unroll
            for (int j = 0; j < 8; ++j)
                u.us[j] = f2bf(tile[c + j][wq] * sl[c + j]);
            *(uint4*)(xt + ((size_t)(b*4096 + h*64 + wq)*512 + c0 + c)) = u.q;
        }
        __syncthreads();
    }
}

// ---------------- kernel 5: implicit-GEMM MFMA conv -----------------------
// block: 64 o x 256 px (4 rows), 4 waves; wave = 64 o x 64 px x 1 row.
// xs LDS: double-buffered [6 rows][64 cols][4 slots(8ch)] = 2 x 24,576 B,
// slot s at pixel p holds ch-group s ^ ((p>>1)&3) (conflict-free b128 reads).
// 3 blocks/CU (147 KB LDS). Tap stream software-pipelined 2-deep.
__global__ __launch_bounds__(256, 3)
void k_conv(const unsigned short* __restrict__ xt, const unsigned short* __restrict__ cwt,
            const float* __restrict__ sig, const float* __restrict__ nw,
            const float* __restrict__ bias, const float* __restrict__ noise,
            float* __restrict__ out) {
    __shared__ __align__(16) short xs_s[2][6*64*32];    // 2 x 24,576 B

    const int tid  = threadIdx.x;
    const int lane = tid & 63;
    const int wave = tid >> 6;
    const int quad = lane >> 4;
    const int l15  = lane & 15;

    // Dispatch swizzle: chunk = XCD (flat&7), 256 blocks/chunk. Within
    // chunk: pxblk fastest, oblk mid (cwt slab reuse), b slowest.
    const int flat  = blockIdx.x;
    const int chunk = flat & 7, idx = flat >> 3;        // idx 0..255
    const int pxblk = idx & 15;
    const int oblk  = (idx >> 4) & 7;
    const int b     = chunk*2 + (idx >> 7);
    const int o0 = oblk * 64, h0 = pxblk * 4;

    // zero the out-of-image rows in BOTH buffers (never staged, any ic)
    if (h0 == 0)
        for (int i = tid; i < 1024; i += 256) {
            ((unsigned int*)xs_s[0])[i] = 0u;
            ((unsigned int*)xs_s[1])[i] = 0u;
        }
    if (h0 == 60)
        for (int i = tid; i < 1024; i += 256) {
            ((unsigned int*)xs_s[0])[5*1024 + i] = 0u;
            ((unsigned int*)xs_s[1])[5*1024 + i] = 0u;
        }

    // staging lane decomposition: lane = 4*pp + s covers px p0+pp, slot s;
    // slot s holds ch-group s ^ ((p>>1)&3) = s ^ ((pp>>1)&3)  (p0 mult 16)
    const int pp = lane >> 2;
    const int cg = (lane & 3) ^ ((lane >> 3) & 3);

    // hoisted staging slot table (fully unrolled refs -> stays in registers)
    const unsigned short* sgp[6];
    int  sdo[6];
    bool sv [6];
#pragma unroll
    for (int k = 0; k < 6; ++k) {
        int q = wave + 4*k, r = q >> 2, p0 = (q & 3) << 4;
        int gr = h0 - 1 + r;
        sv[k]  = (gr >= 0 && gr < 64);
        sgp[k] = xt + ((size_t)(b*4096 + gr*64 + p0 + pp)*512 + cg*8);
        sdo[k] = (r*64 + p0)*32;
    }
#define STAGE(bufidx, icn) do { _Pragma("unroll")                            \
        for (int k_ = 0; k_ < 6; ++k_)                                       \
            if (sv[k_]) gl_lds16(sgp[k_] + (icn)*32, xs_s[bufidx] + sdo[k_]);\
        } while (0)

    f32x4 acc[4][4];
#pragma unroll
    for (int mt = 0; mt < 4; ++mt)
#pragma unroll
        for (int nt = 0; nt < 4; ++nt) acc[mt][nt] = (f32x4){0.f,0.f,0.f,0.f};

    // per-thread base inside the (oblk,ic) slab: + g(quad)*512 + l15*8
    const unsigned short* cwp = cwt + (size_t)oblk*294912 + (size_t)quad*512
                                    + (size_t)l15*8;

    // per-dx column bases (ic-invariant): image col of nt-frag = cs + nt*16
    // - 16; slot swizzle f(c)=(c>>1)&3 invariant under +-16.
    const int wb  = wave * 256;
    const int cs0 = l15 + 15, c0 = wb + cs0*4 + (quad ^ ((cs0 >> 1) & 3));
    const int cs1 = l15 + 16, c1 = wb + cs1*4 + (quad ^ ((cs1 >> 1) & 3));
    const int cs2 = l15 + 17, c2 = wb + cs2*4 + (quad ^ ((cs2 >> 1) & 3));
    const bool e0 = (l15 == 0), e2 = (l15 == 15);

    STAGE(0, 0);
    __syncthreads();

    short8 A0[4], A1[4], B0[4], B1[4];
    const short8 z8 = {};

#define LDA(dst, ptr, tap) { _Pragma("unroll")                               \
        for (int mt_ = 0; mt_ < 4; ++mt_)                                    \
            dst[mt_] = *(const short8*)((ptr) + (tap)*2048 + mt_*128); }

    // B-frags: dst[nt] = xs row (wave+d), cols c##dx + (nt-1)*64 slots
#define LDB0(dst, d) { const int b_ = c0 + (d)*256;                          \
        int a0_ = e0 ? b_ : b_ - 64;                                         \
        dst[0] = xp[a0_];      dst[1] = xp[b_];                              \
        dst[2] = xp[b_ + 64];  dst[3] = xp[b_ + 128];                        \
        if (e0) dst[0] = z8; }
#define LDB1(dst, d) { const int b_ = c1 + (d)*256;                          \
        dst[0] = xp[b_ - 64];  dst[1] = xp[b_];                              \
        dst[2] = xp[b_ + 64];  dst[3] = xp[b_ + 128]; }
#define LDB2(dst, d) { const int b_ = c2 + (d)*256;                          \
        int a3_ = e2 ? b_ : b_ + 128;                                        \
        dst[0] = xp[b_ - 64];  dst[1] = xp[b_];                              \
        dst[2] = xp[b_ + 64];  dst[3] = xp[a3_];                             \
        if (e2) dst[3] = z8; }

#define TAP(AF, BF) { _Pragma("unroll")                                      \
        for (int mt_ = 0; mt_ < 4; ++mt_) { _Pragma("unroll")                \
            for (int nt_ = 0; nt_ < 4; ++nt_)                                \
                acc[mt_][nt_] = __builtin_amdgcn_mfma_f32_16x16x32_bf16(     \
                    AF[mt_], BF[nt_], acc[mt_][nt_], 0, 0, 0); } }

    LDA(A0, cwp, 0);                    // prologue: A(ic=0, tap0)

    for (int ic = 0; ic < 16; ++ic) {
        const short8* xp = (const short8*)xs_s[ic & 1];
        if (ic < 15) STAGE((ic + 1) & 1, ic + 1);    // lands under compute
        const unsigned short* cwn = (ic < 15) ? cwp + 18432 : cwp;

        // 9 tap-stages, 2-deep pipelined: issue s+1 loads, exec s's TAP.
        // tap = dy*3+dx; stage order dx-major: (0,0)(1,0)(2,0)(0,1)...
        LDB0(B0, 0);                                  // s0 B
        LDA(A1, cwp, 3);  LDB0(B1, 1);  TAP(A0, B0);  // s1 in, s0 exec
        LDA(A0, cwp, 6);  LDB0(B0, 2);  TAP(A1, B1);  // s2 in, s1 exec
        LDA(A1, cwp, 1);  LDB1(B1, 0);  TAP(A0, B0);  // s3 in, s2 exec
        LDA(A0, cwp, 4);  LDB1(B0, 1);  TAP(A1, B1);  // s4 in, s3 exec
        LDA(A1, cwp, 7);  LDB1(B1, 2);  TAP(A0, B0);  // s5 in, s4 exec
        LDA(A0, cwp, 2);  LDB2(B0, 0);  TAP(A1, B1);  // s6 in, s5 exec
        LDA(A1, cwp, 5);  LDB2(B1, 1);  TAP(A0, B0);  // s7 in, s6 exec
        LDA(A0, cwp, 8);  LDB2(B0, 2);  TAP(A1, B1);  // s8 in, s7 exec
        TAP(A0, B0);                                  // s8 exec
        LDA(A0, cwn, 0);                              // next-ic s0 A prefetch
        cwp = cwn;
        __syncthreads();   // xs[ic] free; staged xs[ic+1] drained
    }
#undef TAP
#undef LDB0
#undef LDB1
#undef LDB2
#undef LDA
#undef STAGE

    // ---- epilogue: sigma scale + noise + bias + leaky relu ----
    const int h = h0 + wave;
    float nz[4];
#pragma unroll
    for (int nt = 0; nt < 4; ++nt) nz[nt] = noise[b*4096 + h*64 + nt*16 + l15];
#pragma unroll
    for (int mt = 0; mt < 4; ++mt) {
#pragma unroll
        for (int r = 0; r < 4; ++r) {
            int o = o0 + mt*16 + quad*4 + r;
            float sg  = sig[b*512 + o];
            float nwv = nw[o], bv = bias[o];
#pragma unroll
            for (int nt = 0; nt < 4; ++nt) {
                float v = acc[mt][nt][r] * sg + nwv * nz[nt] + bv;
                v = (v >= 0.f) ? v : 0.2f * v;
                out[((size_t)(b*512 + o)*4096) + h*64 + nt*16 + l15] = v;
            }
        }
    }
}

// ---------------------------------------------------------------------------
extern "C" void kernel_launch(void* const* d_in, const int* in_sizes, int n_in,
                              void* d_out, int out_size, void* d_ws, size_t ws_size,
                              hipStream_t stream) {
    const float* x     = (const float*)d_in[0];
    const float* w     = (const float*)d_in[1];
    const float* sw    = (const float*)d_in[2];
    const float* sb    = (const float*)d_in[3];
    const float* cw    = (const float*)d_in[4];
    const float* nw    = (const float*)d_in[5];
    const float* bias  = (const float*)d_in[6];
    const float* noise = (const float*)d_in[7];
    float* out = (float*)d_out;

    char* ws = (char*)d_ws;
    unsigned short* xt  = (unsigned short*)(ws + 0);          // 67,108,864 B
    unsigned short* cwt = (unsigned short*)(ws + 67108864);   //  4,718,592 B
    float* s   = (float*)(ws + 71827456);                     //     32,768 B
    float* sig = (float*)(ws + 71860224);                     //     32,768 B
    float* csq = (float*)(ws + 71892992);                     //  1,048,576 B

    k_wprep<<<512, 256, 0, stream>>>(cw, csq, cwt);
    k_style<<<dim3(8, 16), 256, 0, stream>>>(w, sw, sb, s);
    k_sigma<<<dim3(8, 16), 256, 0, stream>>>(s, csq, sig);
    k_xt   <<<dim3(64, 16), 256, 0, stream>>>(x, s, xt);
    k_conv <<<dim3(2048), 256, 0, stream>>>(xt, cwt, sig, nw, bias, noise, out);
}